// Round 8
// baseline (71.821 us; speedup 1.0000x reference)
//
#include <hip/hip_runtime.h>

typedef __attribute__((ext_vector_type(8))) short short8;
typedef __attribute__((ext_vector_type(16))) float f32x16;
typedef __attribute__((ext_vector_type(2))) float f32x2;
typedef __attribute__((ext_vector_type(2))) unsigned int uint2v;

#define HW 1026
#define CH_STRIDE (HW * HW)          /* 1052676 */
#define TH 16                        /* output rows per tile  */
#define TW 32                        /* output cols per tile  */
#define LDS_ROWS 18                  /* TH + 2 halo           */
#define ROW_BYTES 1088               /* 34 px * 16ch * 2B     */
#define TILE_BYTES (LDS_ROWS * ROW_BYTES)   /* 19584 */
#define UNITS_PER_C4 (LDS_ROWS * 17) /* 306 units of 4ch x 2px */
#define NUNITS (4 * UNITS_PER_C4)    /* 1224 */
#define T_TILES 4                    /* vertical tiles per block */

__device__ __forceinline__ unsigned short f2bf(float f) {
    unsigned int u = __builtin_bit_cast(unsigned int, f);
    u += 0x7fffu + ((u >> 16) & 1u);
    return (unsigned short)(u >> 16);
}

// producer-only: stage one 18x34 tile (fp32 planar -> bf16 [row][px][16ch], swizzled)
__device__ __forceinline__ void stage_tile(const float* __restrict__ x, int h0, int w0,
                                           int ptid, unsigned char* __restrict__ buf) {
    f32x2 vals[5][4];
    #pragma unroll
    for (int k = 0; k < 5; ++k) {                 // issue all loads first
        const int idx = ptid + k * 256;
        if (idx < NUNITS) {
            const int c4  = idx / UNITS_PER_C4;
            const int rem = idx - c4 * UNITS_PER_C4;
            const int row = rem / 17;
            const int u   = rem - row * 17;
            const float* base = x + (4 * c4) * CH_STRIDE + (h0 + row) * HW + (w0 + 2 * u);
            #pragma unroll
            for (int j = 0; j < 4; ++j)
                vals[k][j] = *(const f32x2*)(base + j * CH_STRIDE);
        }
    }
    #pragma unroll
    for (int k = 0; k < 5; ++k) {                 // then convert + ds_write
        const int idx = ptid + k * 256;
        if (idx < NUNITS) {
            const int c4  = idx / UNITS_PER_C4;
            const int rem = idx - c4 * UNITS_PER_C4;
            const int row = rem / 17;
            const int u   = rem - row * 17;
            #pragma unroll
            for (int p = 0; p < 2; ++p) {
                const int pp = 2 * u + p;
                const unsigned int lo  = (unsigned int)f2bf(vals[k][0][p]) |
                                         ((unsigned int)f2bf(vals[k][1][p]) << 16);
                const unsigned int hi2 = (unsigned int)f2bf(vals[k][2][p]) |
                                         ((unsigned int)f2bf(vals[k][3][p]) << 16);
                const int s16 = ((c4 >> 1) ^ (pp >> 2) ^ (pp >> 3)) & 1;
                const int off = row * ROW_BYTES + pp * 32 + s16 * 16 + (c4 & 1) * 8;
                uint2v t; t.x = lo; t.y = hi2;
                *(uint2v*)(buf + off) = t;
            }
        }
    }
}

// consumer-only: 36 MFMAs + coalesced nt stores for one tile
__device__ __forceinline__ void compute_store(const unsigned char* __restrict__ buf,
                                              const short8 (&af)[3][3],
                                              float* __restrict__ out,
                                              int h0, int w0, int cw, int n, int hi) {
    #pragma unroll
    for (int t = 0; t < 4; ++t) {
        const int baserow = cw * 4 + t;
        f32x16 acc;
        #pragma unroll
        for (int q = 0; q < 16; ++q) acc[q] = 0.0f;
        #pragma unroll
        for (int r = 0; r < 3; ++r) {
            #pragma unroll
            for (int s = 0; s < 3; ++s) {
                const int w   = n + s;
                const int s16 = (hi ^ (w >> 2) ^ (w >> 3)) & 1;
                const int off = (baserow + r) * ROW_BYTES + w * 32 + s16 * 16;
                const short8 bfr = *(const short8*)(buf + off);   // ds_read_b128
                acc = __builtin_amdgcn_mfma_f32_32x32x16_bf16(af[r][s], bfr, acc, 0, 0, 0);
            }
        }
        // C/D: col(lane&31)=pixel, row(q)=(q&3)+8*(q>>2)+4*hi = outch
        const int h = h0 + baserow;
        #pragma unroll
        for (int q = 0; q < 16; ++q) {
            const int o = (q & 3) + 8 * (q >> 2) + 4 * hi;
            __builtin_nontemporal_store(acc[q], out + (o << 20) + (h << 10) + (w0 + n));
        }
    }
}

__global__ __launch_bounds__(512, 4)
void gck3x3_mfma_kernel(const float* __restrict__ x,
                        const float* __restrict__ kern,
                        float* __restrict__ out) {
    __shared__ __attribute__((aligned(16))) unsigned char s_x[2][TILE_BYTES];

    const int tid      = threadIdx.x;
    const bool producer = tid < 256;
    const int ptid     = tid & 255;          // producer lane-group id
    const int lane     = tid & 63;
    const int cw       = (tid >> 6) - 4;     // consumer wave 0..3
    const int n        = lane & 31;
    const int hi       = lane >> 5;

    // XCD-aware bijective swizzle: 512 blocks = 8 * 64
    const int bid = blockIdx.x;
    const int swz = (bid & 7) * 64 + (bid >> 3);
    const int h_base = (swz >> 5) * (T_TILES * TH);  // 16 chunks of 64 rows
    const int w0     = (swz & 31) * TW;

    short8 af[3][3];
    if (producer) {
        stage_tile(x, h_base, w0, ptid, &s_x[0][0]);
    } else {
        // weight fragments: W[o=n][c=8*hi+j][r][s], L2-resident (overlaps staging)
        #pragma unroll
        for (int r = 0; r < 3; ++r)
            #pragma unroll
            for (int s = 0; s < 3; ++s) {
                short8 v;
                #pragma unroll
                for (int j = 0; j < 8; ++j)
                    v[j] = (short)f2bf(kern[n * 144 + (8 * hi + j) * 9 + r * 3 + s]);
                af[r][s] = v;
            }
    }
    __syncthreads();

    #pragma unroll
    for (int j = 0; j < T_TILES; ++j) {
        if (producer) {
            if (j + 1 < T_TILES)
                stage_tile(x, h_base + (j + 1) * TH, w0, ptid, &s_x[(j + 1) & 1][0]);
        } else {
            compute_store(&s_x[j & 1][0], af, out, h_base + j * TH, w0, cw, n, hi);
        }
        __syncthreads();
    }
}

extern "C" void kernel_launch(void* const* d_in, const int* in_sizes, int n_in,
                              void* d_out, int out_size, void* d_ws, size_t ws_size,
                              hipStream_t stream) {
    (void)in_sizes; (void)n_in; (void)d_ws; (void)ws_size; (void)out_size;
    const float* x    = (const float*)d_in[0];
    const float* kern = (const float*)d_in[1];
    float*       out  = (float*)d_out;
    gck3x3_mfma_kernel<<<512, 512, 0, stream>>>(x, kern, out);
}

// Round 9
// 40.108 us; speedup vs baseline: 1.7907x; 1.7907x over previous
//
#include <hip/hip_runtime.h>

typedef __attribute__((ext_vector_type(8))) short short8;
typedef __attribute__((ext_vector_type(16))) float f32x16;
typedef __attribute__((ext_vector_type(2))) float f32x2;
typedef __attribute__((ext_vector_type(2))) unsigned int uint2v;

#define HW 1026
#define CH_STRIDE (HW * HW)           /* 1052676 */
#define TH 8                          /* output rows per block  */
#define TW 128                        /* output cols per block  */
#define LDS_ROWS 10                   /* TH + 2 halo            */
#define LDS_PX 130                    /* TW + 2 halo            */
#define ROW_BYTES (LDS_PX * 32)       /* 4160 B                 */
#define X_LDS (LDS_ROWS * ROW_BYTES)  /* 41600 B                */
#define W_LDS (9 * 32 * 16 * 2)       /* 9216 B: [rs][o][c] bf16 */
#define UNITS_PER_C4 (LDS_ROWS * 65)  /* 650 units of 4ch x 2px */
#define NUNITS (4 * UNITS_PER_C4)     /* 2600 */

__device__ __forceinline__ unsigned short f2bf(float f) {
    unsigned int u = __builtin_bit_cast(unsigned int, f);
    u += 0x7fffu + ((u >> 16) & 1u);
    return (unsigned short)(u >> 16);
}

template<int K0, int NR>
__device__ __forceinline__ void issue_rounds(const float* __restrict__ x, int h0, int w0,
                                             int tid, f32x2 (&vals)[NR][4]) {
    #pragma unroll
    for (int k = 0; k < NR; ++k) {
        const int idx = tid + (K0 + k) * 256;
        if (idx < NUNITS) {
            const int c4  = idx / UNITS_PER_C4;
            const int rem = idx - c4 * UNITS_PER_C4;
            const int row = rem / 65;
            const int u   = rem - row * 65;
            const float* base = x + (4 * c4) * CH_STRIDE + (h0 + row) * HW + (w0 + 2 * u);
            #pragma unroll
            for (int j = 0; j < 4; ++j)
                vals[k][j] = *(const f32x2*)(base + j * CH_STRIDE);
        }
    }
}

template<int K0, int NR>
__device__ __forceinline__ void conv_rounds(unsigned char* __restrict__ sx, int tid,
                                            const f32x2 (&vals)[NR][4]) {
    #pragma unroll
    for (int k = 0; k < NR; ++k) {
        const int idx = tid + (K0 + k) * 256;
        if (idx < NUNITS) {
            const int c4  = idx / UNITS_PER_C4;
            const int rem = idx - c4 * UNITS_PER_C4;
            const int row = rem / 65;
            const int u   = rem - row * 65;
            #pragma unroll
            for (int p = 0; p < 2; ++p) {
                const int pp = 2 * u + p;
                const unsigned int lo  = (unsigned int)f2bf(vals[k][0][p]) |
                                         ((unsigned int)f2bf(vals[k][1][p]) << 16);
                const unsigned int hi2 = (unsigned int)f2bf(vals[k][2][p]) |
                                         ((unsigned int)f2bf(vals[k][3][p]) << 16);
                const int s16 = ((c4 >> 1) ^ (pp >> 2) ^ (pp >> 3)) & 1;
                const int off = row * ROW_BYTES + pp * 32 + s16 * 16 + (c4 & 1) * 8;
                uint2v t; t.x = lo; t.y = hi2;
                *(uint2v*)(sx + off) = t;
            }
        }
    }
}

__global__ __launch_bounds__(256, 4)
void gck3x3_mfma_kernel(const float* __restrict__ x,
                        const float* __restrict__ kern,
                        float* __restrict__ out) {
    __shared__ __attribute__((aligned(16))) unsigned char s_mem[X_LDS + W_LDS];
    unsigned char* s_x = s_mem;
    unsigned char* s_w = s_mem + X_LDS;

    const int tid  = threadIdx.x;
    const int lane = tid & 63;
    const int wv   = tid >> 6;      // 0..3: 32-px column group
    const int n    = lane & 31;     // outch (A) / pixel-within-group (B, store)
    const int hi   = lane >> 5;     // k half: channels 8*hi..8*hi+7

    // XCD swizzle: 1024 = 8*128; each XCD owns one 128-px column strip,
    // walking vertically (halo + column-band reuse in its private L2)
    const int bid = blockIdx.x;
    const int swz = (bid & 7) * 128 + (bid >> 3);
    const int bw  = swz >> 7;           // 0..7
    const int bh  = swz & 127;          // 0..127
    const int h0  = bh * TH;
    const int w0  = bw * TW;

    // ---- weights once per block: kern (4608 f32) -> s_w[rs][o][c] bf16 ----
    {
        float wv_[18];
        #pragma unroll
        for (int k = 0; k < 18; ++k)
            wv_[k] = kern[tid + 256 * k];          // coalesced, L2-hot
        #pragma unroll
        for (int k = 0; k < 18; ++k) {
            const int idx = tid + 256 * k;
            const int o   = idx / 144;
            const int rm  = idx - o * 144;
            const int c   = rm / 9;
            const int rs  = rm - c * 9;
            *(short*)(s_w + rs * 1024 + o * 32 + c * 2) = (short)f2bf(wv_[k]);
        }
    }

    // ---- x staging: 11 rounds in 3 chunks (issue/convert pipelined) ----
    {
        f32x2 vA[4][4], vB[4][4], vC[3][4];
        issue_rounds<0, 4>(x, h0, w0, tid, vA);
        issue_rounds<4, 4>(x, h0, w0, tid, vB);
        conv_rounds<0, 4>(s_x, tid, vA);
        issue_rounds<8, 3>(x, h0, w0, tid, vC);
        conv_rounds<4, 4>(s_x, tid, vB);
        conv_rounds<8, 3>(s_x, tid, vC);
    }
    __syncthreads();

    // ---- A fragments from LDS: af[rs] = W[o=n][c=8hi..+7][rs] ----
    short8 af[9];
    #pragma unroll
    for (int rs = 0; rs < 9; ++rs)
        af[rs] = *(const short8*)(s_w + rs * 1024 + n * 32 + hi * 16);

    // ---- compute: per row t, 9 MFMAs; block writes 512 B per (o,h) ----
    #pragma unroll
    for (int t = 0; t < TH; ++t) {
        f32x16 acc;
        #pragma unroll
        for (int q = 0; q < 16; ++q) acc[q] = 0.0f;

        #pragma unroll
        for (int r = 0; r < 3; ++r) {
            #pragma unroll
            for (int s = 0; s < 3; ++s) {
                const int pxl = wv * 32 + n + s;
                const int p   = ((pxl >> 2) ^ (pxl >> 3)) & 1;
                const int off = (t + r) * ROW_BYTES + pxl * 32 + ((hi ^ p) & 1) * 16;
                const short8 bfr = *(const short8*)(s_x + off);   // ds_read_b128
                acc = __builtin_amdgcn_mfma_f32_32x32x16_bf16(af[r * 3 + s], bfr, acc, 0, 0, 0);
            }
        }

        // C/D: col(lane&31)=pixel, row(q)=(q&3)+8*(q>>2)+4*hi = outch
        // PLAIN stores this round (A/B vs R7's nontemporal): let L2/L3
        // writeback buffer the stream like fillBuffer's 6.9 TB/s path.
        const int h = h0 + t;
        float* obase = out + (h << 10) + w0 + wv * 32 + n;
        #pragma unroll
        for (int q = 0; q < 16; ++q) {
            const int o = (q & 3) + 8 * (q >> 2) + 4 * hi;
            obase[o << 20] = acc[q];
        }
    }
}

extern "C" void kernel_launch(void* const* d_in, const int* in_sizes, int n_in,
                              void* d_out, int out_size, void* d_ws, size_t ws_size,
                              hipStream_t stream) {
    (void)in_sizes; (void)n_in; (void)d_ws; (void)ws_size; (void)out_size;
    const float* x    = (const float*)d_in[0];
    const float* kern = (const float*)d_in[1];
    float*       out  = (float*)d_out;
    gck3x3_mfma_kernel<<<1024, 256, 0, stream>>>(x, kern, out);
}

// Round 10
// 38.409 us; speedup vs baseline: 1.8699x; 1.0442x over previous
//
#include <hip/hip_runtime.h>

typedef __attribute__((ext_vector_type(8))) short short8;
typedef __attribute__((ext_vector_type(16))) float f32x16;
typedef __attribute__((ext_vector_type(2))) float f32x2;
typedef __attribute__((ext_vector_type(2))) unsigned int uint2v;

#define HW 1026
#define CH_STRIDE (HW * HW)           /* 1052676 */
#define TH 32                         /* output rows per block  */
#define TW 32                         /* output cols per block  */
#define LDS_ROWS 34                   /* TH + 2 halo            */
#define LDS_PX 34                     /* TW + 2 halo            */
#define ROW_BYTES (LDS_PX * 32)       /* 1088 B                 */
#define X_LDS (LDS_ROWS * ROW_BYTES)  /* 36992 B -> 4 blocks/CU */
#define UNITS_PER_C4 (LDS_ROWS * 17)  /* 578 units of 4ch x 2px */
#define NUNITS (4 * UNITS_PER_C4)     /* 2312 */

__device__ __forceinline__ unsigned short f2bf(float f) {
    unsigned int u = __builtin_bit_cast(unsigned int, f);
    u += 0x7fffu + ((u >> 16) & 1u);
    return (unsigned short)(u >> 16);
}

template<int K0, int NR>
__device__ __forceinline__ void issue_rounds(const float* __restrict__ x, int h0, int w0,
                                             int tid, f32x2 (&vals)[NR][4]) {
    #pragma unroll
    for (int k = 0; k < NR; ++k) {
        const int idx = tid + (K0 + k) * 256;
        if (idx < NUNITS) {
            const int c4  = idx / UNITS_PER_C4;
            const int rem = idx - c4 * UNITS_PER_C4;
            const int row = rem / 17;
            const int u   = rem - row * 17;
            const float* base = x + (4 * c4) * CH_STRIDE + (h0 + row) * HW + (w0 + 2 * u);
            #pragma unroll
            for (int j = 0; j < 4; ++j)
                vals[k][j] = *(const f32x2*)(base + j * CH_STRIDE);
        }
    }
}

template<int K0, int NR>
__device__ __forceinline__ void conv_rounds(unsigned char* __restrict__ sx, int tid,
                                            const f32x2 (&vals)[NR][4]) {
    #pragma unroll
    for (int k = 0; k < NR; ++k) {
        const int idx = tid + (K0 + k) * 256;
        if (idx < NUNITS) {
            const int c4  = idx / UNITS_PER_C4;
            const int rem = idx - c4 * UNITS_PER_C4;
            const int row = rem / 17;
            const int u   = rem - row * 17;
            #pragma unroll
            for (int p = 0; p < 2; ++p) {
                const int pp = 2 * u + p;
                const unsigned int lo  = (unsigned int)f2bf(vals[k][0][p]) |
                                         ((unsigned int)f2bf(vals[k][1][p]) << 16);
                const unsigned int hi2 = (unsigned int)f2bf(vals[k][2][p]) |
                                         ((unsigned int)f2bf(vals[k][3][p]) << 16);
                const int s16 = ((c4 >> 1) ^ (pp >> 2) ^ (pp >> 3)) & 1;
                const int off = row * ROW_BYTES + pp * 32 + s16 * 16 + (c4 & 1) * 8;
                uint2v t; t.x = lo; t.y = hi2;
                *(uint2v*)(sx + off) = t;
            }
        }
    }
}

__global__ __launch_bounds__(256, 4)
void gck3x3_mfma_kernel(const float* __restrict__ x,
                        const float* __restrict__ kern,
                        float* __restrict__ out) {
    __shared__ __attribute__((aligned(16))) unsigned char s_x[X_LDS];

    const int tid  = threadIdx.x;
    const int lane = tid & 63;
    const int wv   = tid >> 6;      // 0..3: owns 8 output rows
    const int n    = lane & 31;     // outch (A-frag) / pixel (B-frag, store)
    const int hi   = lane >> 5;     // k half: channels 8*hi..8*hi+7

    // XCD-aware bijective swizzle: 1024 = 8*128; each XCD walks 4 full
    // tile-rows (vertical neighbors share halo rows in its private L2)
    const int bid = blockIdx.x;
    const int swz = (bid & 7) * 128 + (bid >> 3);
    const int h0  = (swz >> 5) * TH;   // 0..992
    const int w0  = (swz & 31) * TW;   // 0..992

    // ---- x staging: 10 rounds in 3 chunks (issue/convert pipelined) ----
    {
        f32x2 vA[4][4], vB[4][4], vC[2][4];
        issue_rounds<0, 4>(x, h0, w0, tid, vA);
        issue_rounds<4, 4>(x, h0, w0, tid, vB);
        conv_rounds<0, 4>(s_x, tid, vA);
        issue_rounds<8, 2>(x, h0, w0, tid, vC);
        conv_rounds<4, 4>(s_x, tid, vB);
        conv_rounds<8, 2>(s_x, tid, vC);
    }

    // ---- weight fragments, direct VMEM (L2-hot): W[o=n][c=8hi+j][r][s] ----
    short8 af[3][3];
    #pragma unroll
    for (int r = 0; r < 3; ++r) {
        #pragma unroll
        for (int s = 0; s < 3; ++s) {
            short8 v;
            #pragma unroll
            for (int j = 0; j < 8; ++j)
                v[j] = (short)f2bf(kern[n * 144 + (8 * hi + j) * 9 + r * 3 + s]);
            af[r][s] = v;
        }
    }
    __syncthreads();

    // ---- compute: rolling acc over 8 rows per wave, 9 MFMAs each ----
    #pragma unroll
    for (int t = 0; t < 8; ++t) {
        const int baserow = wv * 8 + t;
        f32x16 acc;
        #pragma unroll
        for (int q = 0; q < 16; ++q) acc[q] = 0.0f;

        #pragma unroll
        for (int r = 0; r < 3; ++r) {
            #pragma unroll
            for (int s = 0; s < 3; ++s) {
                const int w   = n + s;
                const int s16 = (hi ^ (w >> 2) ^ (w >> 3)) & 1;
                const int off = (baserow + r) * ROW_BYTES + w * 32 + s16 * 16;
                const short8 bfr = *(const short8*)(s_x + off);   // ds_read_b128
                acc = __builtin_amdgcn_mfma_f32_32x32x16_bf16(af[r][s], bfr, acc, 0, 0, 0);
            }
        }

        // C/D: col(lane&31)=pixel, row(q)=(q&3)+8*(q>>2)+4*hi = outch
        // plain stores (R9 win: L2/L3 writeback buffers the 32-plane stream)
        const int h = h0 + baserow;
        float* obase = out + (h << 10) + w0 + n;
        #pragma unroll
        for (int q = 0; q < 16; ++q) {
            const int o = (q & 3) + 8 * (q >> 2) + 4 * hi;
            obase[o << 20] = acc[q];
        }
    }
}

extern "C" void kernel_launch(void* const* d_in, const int* in_sizes, int n_in,
                              void* d_out, int out_size, void* d_ws, size_t ws_size,
                              hipStream_t stream) {
    (void)in_sizes; (void)n_in; (void)d_ws; (void)ws_size; (void)out_size;
    const float* x    = (const float*)d_in[0];
    const float* kern = (const float*)d_in[1];
    float*       out  = (float*)d_out;
    gck3x3_mfma_kernel<<<1024, 256, 0, stream>>>(x, kern, out);
}